// Round 8
// baseline (346.155 us; speedup 1.0000x reference)
//
#include <hip/hip_runtime.h>
#include <hip/hip_bf16.h>

// Problem constants: B=2, S=2048, HID=2048, H=16, HD=128, HD2=64, LAT=256
#define BB 2
#define SS 2048
#define HID 2048
#define NH 16
#define BS (BB*SS)          // 4096 rows
#define SCALE 0.088388347648318447f   // 1/sqrt(128)
#define C2LOG 0.12751743f              // SCALE * log2(e)

typedef __bf16 bf16x8 __attribute__((ext_vector_type(8)));
typedef float f32x4 __attribute__((ext_vector_type(4)));
typedef float f32x16 __attribute__((ext_vector_type(16)));
typedef unsigned int uintx2 __attribute__((ext_vector_type(2)));

__device__ __forceinline__ bf16x8 ld_frag(const __hip_bfloat16* p) {
    uint4 u = *reinterpret_cast<const uint4*>(p);
    return __builtin_bit_cast(bf16x8, u);
}
// HW packed f32->bf16 convert (RNE). gfx950 has no builtin (m240): inline asm.
__device__ __forceinline__ unsigned int cvt_pk_bf16(float a, float b) {
    unsigned int r;
    asm("v_cvt_pk_bf16_f32 %0, %1, %2" : "=v"(r) : "v"(a), "v"(b));
    return r;
}
__device__ __forceinline__ ushort bf_bits(float v) {
    return (ushort)cvt_pk_bf16(v, v);
}
__device__ __forceinline__ void store_c(__hip_bfloat16* C, size_t idx, float v) {
    *reinterpret_cast<ushort*>(&C[idx]) = bf_bits(v);
}
__device__ __forceinline__ void store_c(float* C, size_t idx, float v) {
    C[idx] = v;
}

// async global->LDS, 16B per lane; lds addr must be wave-uniform base + lane*16
#define GLD16(gp, lp) \
  __builtin_amdgcn_global_load_lds((const __attribute__((address_space(1))) void*)(gp), \
                                   (__attribute__((address_space(3))) void*)(lp), 16, 0, 0)

// ---------------------------------------------------------------------------
// Fragment-order global layouts (v13, kept).
// Kf: element K[b][kv][h][d] ->
//   (b*16+h)*262144 + (kv>>5)*4096 + (d>>4)*512 + ((d>>3)&1)*256 + (kv&31)*8 + (d&7)
// Vf: element V[b][kv][h][d] ->
//   (b*16+h)*262144 + (kv>>6)*8192 + (d>>5)*2048 + ((kv>>4)&3)*512
//   + ((kv>>3)&1)*256 + (d&31)*8 + (kv&7)
// ---------------------------------------------------------------------------

// ---------------------------------------------------------------------------
// fp32 -> bf16 flat convert (hs)
// ---------------------------------------------------------------------------
__global__ __launch_bounds__(256) void convert_kernel(
    const float* __restrict__ src, __hip_bfloat16* __restrict__ dst, int n8)
{
    int i = blockIdx.x * blockDim.x + threadIdx.x;
    if (i >= n8) return;
    float4 a = reinterpret_cast<const float4*>(src)[2 * i];
    float4 b = reinterpret_cast<const float4*>(src)[2 * i + 1];
    uint4 o;
    o.x = cvt_pk_bf16(a.x, a.y);
    o.y = cvt_pk_bf16(a.z, a.w);
    o.z = cvt_pk_bf16(b.x, b.y);
    o.w = cvt_pk_bf16(b.z, b.w);
    reinterpret_cast<uint4*>(dst)[i] = o;
}

// ---------------------------------------------------------------------------
// Fused weight transpose+convert: 8 segments, src fp32 [R][C] -> dst bf16 [C][R]
// ---------------------------------------------------------------------------
__global__ __launch_bounds__(256) void transpose_weights_kernel(
    const float* s0, const float* s1, const float* s2, const float* s3,
    const float* s4, const float* s5, const float* s6, const float* s7,
    __hip_bfloat16* WT1, __hip_bfloat16* WT2, __hip_bfloat16* WT3,
    __hip_bfloat16* WTo)
{
    const float* srcs[8] = { s0, s1, s2, s3, s4, s5, s6, s7 };
    const int Rs[8] = { 2048, 2048, 2048, 256, 256, 256, 256, 2048 };
    const int Cs[8] = { 256, 256, 1024, 1024, 2048, 1024, 1024, 2048 };
    __hip_bfloat16* dsts[8] = {
        WT1, WT1 + (size_t)256 * 2048, WT1 + (size_t)512 * 2048,
        WT2, WT2 + (size_t)1024 * 256,
        WT3, WT3 + (size_t)1024 * 256,
        WTo };
    const int prefix[9] = { 0, 512, 1024, 3072, 3328, 3840, 4096, 4352, 8448 };

    int bid = blockIdx.x;
    int seg = 0;
    #pragma unroll
    for (int i = 0; i < 8; i++) if (bid >= prefix[i + 1]) seg = i + 1;
    int local = bid - prefix[seg];
    int R = Rs[seg], C = Cs[seg];
    int tilesC = C / 32;
    int tr = local / tilesC, tc = local % tilesC;
    int r0 = tr * 32, c0 = tc * 32;
    const float* src = srcs[seg];
    __hip_bfloat16* dst = dsts[seg];

    __shared__ float Ts[32][33];
    int t = threadIdx.x;
    int ty = t >> 5, tx = t & 31;
    #pragma unroll
    for (int k = 0; k < 4; k++) {
        int r = ty + k * 8;
        Ts[r][tx] = src[(size_t)(r0 + r) * C + c0 + tx];
    }
    __syncthreads();
    #pragma unroll
    for (int k = 0; k < 4; k++) {
        int r = ty + k * 8;
        *reinterpret_cast<ushort*>(&dst[(size_t)(c0 + r) * R + r0 + tx]) =
            bf_bits(Ts[tx][r]);
    }
}

// ---------------------------------------------------------------------------
// m97-style GEMM: C = A[M,K] * Bt[N,K]^T, bf16 in, fp32 acc.
// 128x128 tile, BK=32, global_load_lds staging, 4 waves each 64x64.
// + bijective XCD swizzle (T1; all grids here have nwg%8==0).
// Epilogue routing: col < splitN -> (C0,...) else (C1,...). cm = output scale.
//   s64==0: plain col
//   s64==1: col c -> (c>>6)*128 + (c&63) + off (head scatter, row-major)
//   s64==2: transposed store: Cp[c*4096 + row]
//   s64==3: Kf fragment-order scatter; c: h=c>>6, d=off+(c&63); row m: b,kv
//   s64==4: Vf fragment-order scatter; c: h=c>>7, d=c&127;    row m: b,kv
// ---------------------------------------------------------------------------
template <typename TC>
__global__ __launch_bounds__(256) void gemm_bt_kernel(
    const __hip_bfloat16* __restrict__ A, int lda,
    const __hip_bfloat16* __restrict__ Bt,
    TC* __restrict__ C0, int ldc0, int sp0, int off0, float cm0,
    TC* __restrict__ C1, int ldc1, int sp1, int off1, float cm1,
    int splitN, int K)
{
    __shared__ alignas(16) __hip_bfloat16 As[128 * 32];
    __shared__ alignas(16) __hip_bfloat16 Bs[128 * 32];

    // XCD-aware bijective remap (nwg % 8 == 0 for all launches here)
    const int nwg = gridDim.x * gridDim.y;
    int lin = blockIdx.y * gridDim.x + blockIdx.x;
    lin = (lin & 7) * (nwg >> 3) + (lin >> 3);
    const int bn = (lin % gridDim.x) * 128;
    const int bm = (lin / gridDim.x) * 128;

    const int t = threadIdx.x;
    const int w = t >> 6;
    const int lane = t & 63;
    const int l15 = lane & 15;
    const int quad = lane >> 4;
    const int wm = (w & 1) * 64;
    const int wn = (w >> 1) * 64;

    const int srow = lane >> 2;          // 0..15
    const int skcol = (lane & 3) * 8;    // 0,8,16,24

    f32x4 acc[4][4] = {};

    for (int k0 = 0; k0 < K; k0 += 32) {
        __syncthreads();
        #pragma unroll
        for (int i = 0; i < 2; i++) {
            int r = w * 32 + i * 16 + srow;
            GLD16(A + (size_t)(bm + r) * lda + k0 + skcol, &As[r * 32 + skcol]);
            GLD16(Bt + (size_t)(bn + r) * K + k0 + skcol, &Bs[r * 32 + skcol]);
        }
        __syncthreads();

        bf16x8 af[4], bf[4];
        #pragma unroll
        for (int mt = 0; mt < 4; mt++)
            af[mt] = ld_frag(&As[(wm + mt * 16 + l15) * 32 + quad * 8]);
        #pragma unroll
        for (int nt = 0; nt < 4; nt++)
            bf[nt] = ld_frag(&Bs[(wn + nt * 16 + l15) * 32 + quad * 8]);
        #pragma unroll
        for (int mt = 0; mt < 4; mt++)
            #pragma unroll
            for (int nt = 0; nt < 4; nt++)
                acc[mt][nt] = __builtin_amdgcn_mfma_f32_16x16x32_bf16(
                    af[mt], bf[nt], acc[mt][nt], 0, 0, 0);
    }

    #pragma unroll
    for (int nt = 0; nt < 4; nt++) {
        int col = bn + wn + nt * 16 + l15;
        TC* Cp; int c, ld, s64, off; float cm;
        if (col < splitN) { Cp = C0; c = col; ld = ldc0; s64 = sp0; off = off0; cm = cm0; }
        else { Cp = C1; c = col - splitN; ld = ldc1; s64 = sp1; off = off1; cm = cm1; }
        if (s64 == 2) {
            #pragma unroll
            for (int mt = 0; mt < 4; mt++) {
                int row0 = bm + wm + mt * 16 + quad * 4;
                #pragma unroll
                for (int r = 0; r < 4; r++)
                    store_c(Cp, (size_t)c * 4096 + row0 + r, acc[mt][nt][r] * cm);
            }
        } else if (s64 == 3) {
            const int hh = c >> 6, d = off + (c & 63);
            const size_t dbase = (size_t)(d >> 4) * 512
                               + (size_t)((d >> 3) & 1) * 256 + (d & 7);
            #pragma unroll
            for (int mt = 0; mt < 4; mt++) {
                #pragma unroll
                for (int r = 0; r < 4; r++) {
                    int m = bm + wm + mt * 16 + quad * 4 + r;
                    int bb2 = m >> 11, kv = m & 2047;
                    size_t idx = (size_t)(bb2 * 16 + hh) * 262144
                               + (size_t)(kv >> 5) * 4096 + dbase
                               + (size_t)(kv & 31) * 8;
                    store_c(Cp, idx, acc[mt][nt][r] * cm);
                }
            }
        } else if (s64 == 4) {
            const int hh = c >> 7, d = c & 127;
            const size_t dbase = (size_t)(d >> 5) * 2048 + (size_t)(d & 31) * 8;
            #pragma unroll
            for (int mt = 0; mt < 4; mt++) {
                #pragma unroll
                for (int r = 0; r < 4; r++) {
                    int m = bm + wm + mt * 16 + quad * 4 + r;
                    int bb2 = m >> 11, kv = m & 2047;
                    size_t idx = (size_t)(bb2 * 16 + hh) * 262144
                               + (size_t)(kv >> 6) * 8192 + dbase
                               + (size_t)((kv >> 4) & 3) * 512
                               + (size_t)((kv >> 3) & 1) * 256 + (kv & 7);
                    store_c(Cp, idx, acc[mt][nt][r] * cm);
                }
            }
        } else {
            int oc = s64 ? ((c >> 6) * 128 + (c & 63) + off) : c;
            #pragma unroll
            for (int mt = 0; mt < 4; mt++) {
                #pragma unroll
                for (int r = 0; r < 4; r++) {
                    int row = bm + wm + mt * 16 + quad * 4 + r;
                    store_c(Cp, (size_t)row * ld + oc, acc[mt][nt][r] * cm);
                }
            }
        }
    }
}

// ---------------------------------------------------------------------------
// RoPE in-place: K in Kf fragment-order layout, Q in row-major Qbuf.
// Pair (d1=64+i, d2=96+i): in Kf, d2 is exactly +2 regions = +1024 elems.
// ---------------------------------------------------------------------------
__global__ __launch_bounds__(256) void rope_kernel(
    __hip_bfloat16* __restrict__ Kf, __hip_bfloat16* __restrict__ Qb)
{
    int idx = blockIdx.x * blockDim.x + threadIdx.x;
    if (idx >= BS * NH * 32) return;
    int i = idx & 31;
    int h = (idx >> 5) & 15;
    int row = idx >> 9;
    int s = row & (SS - 1);
    int b = row >> 11;

    float inv = exp2f(-(float)i * 0.4152410118609203f);  // 10000^(-i/32)
    float ang = (float)s * inv;
    float sn = sinf(ang), cs = cosf(ang);

    {   // K (Kf layout)
        size_t kaddr = ((size_t)(b * 16 + h) * 64 + (s >> 5)) * 4096
                     + (size_t)(4 + (i >> 4)) * 512
                     + (size_t)(((i >> 3) & 1) * 32 + (s & 31)) * 8 + (i & 7);
        float x1 = __bfloat162float(Kf[kaddr]);
        float x2 = __bfloat162float(Kf[kaddr + 1024]);
        *reinterpret_cast<ushort*>(&Kf[kaddr])        = bf_bits(x1 * cs - x2 * sn);
        *reinterpret_cast<ushort*>(&Kf[kaddr + 1024]) = bf_bits(x1 * sn + x2 * cs);
    }
    {   // Q (row-major)
        size_t obase = (size_t)row * 2048 + h * 128 + 64 + i;
        float x1 = __bfloat162float(Qb[obase]);
        float x2 = __bfloat162float(Qb[obase + 32]);
        *reinterpret_cast<ushort*>(&Qb[obase])      = bf_bits(x1 * cs - x2 * sn);
        *reinterpret_cast<ushort*>(&Qb[obase + 32]) = bf_bits(x1 * sn + x2 * cs);
    }
}

// ---------------------------------------------------------------------------
// Flash attention v15 = v14 compute core + XCD (b,h)-grouping + triple-buffer
// 2-deep prefetch with counted vmcnt(4).
// r7 evidence: cost/iter ~fixed regardless of active waves (Occ 18% = blocks
// finish prop. to nbig) -> binder is the staging drain. Grid (x=p,y=h,z=b)
// put the 8 p-blocks of one (b,h) on 8 DIFFERENT XCDs (xcd = linear%8 = p):
// 8x K/V L2-duplication (FETCH 110MB vs ~48MB unique) + XCD0 got all long
// blocks. v15 decode: p = blockIdx.y&7, h = blockIdx.x + 8*(blockIdx.y>>3),
// b = blockIdx.z -> all 8 p-blocks of a (b,h) share blockIdx.x => same XCD,
// tile-synchronized L2 reuse; long/short blocks mixed across XCDs.
// Triple buffer: stage tile kt+2 each iter, wait vmcnt(4) (tile kt landed,
// kt+1 in flight) -> 2 iterations of latency hiding, 8 loads in flight.
// ---------------------------------------------------------------------------
__global__ __launch_bounds__(512) void flash_attn_kernel(
    const __hip_bfloat16* __restrict__ Q,
    const __hip_bfloat16* __restrict__ Kf,
    const __hip_bfloat16* __restrict__ Vf,
    __hip_bfloat16* __restrict__ O)
{
    __shared__ alignas(16) __hip_bfloat16 Ktd[3 * 16 * 512];  // [buf3][region][slot]
    __shared__ alignas(16) __hip_bfloat16 Vsd[3 * 16 * 512];

    // XCD-grouped decode: same-(b,h) blocks share blockIdx.x -> same XCD.
    const int p = blockIdx.y & 7;                     // pair index 0..7
    const int h = blockIdx.x + 8 * (blockIdx.y >> 3); // head 0..15
    const int b = blockIdx.z;
    const int t = threadIdx.x;
    const int w = t >> 6;                // 0..7
    const int lane = t & 63;
    const int l31 = lane & 31;
    const int hi = lane >> 5;

    const int qt = (w < 4) ? (15 - p) : p;   // this wave's q-tile
    const int wq = w & 3;
    const int qwb = qt * 128 + wq * 32;      // wave's q base (32 rows)
    const int q = qwb + l31;                 // this lane's q row
    const int my_nt = 2 * qt + 1 + (wq >> 1);// kv tiles this wave needs
    const int nbig = 2 * (15 - p) + 2;       // shared loop length (>= 18)

    const __hip_bfloat16* Kfb = Kf + (size_t)(b * 16 + h) * 262144;
    const __hip_bfloat16* Vfb = Vf + (size_t)(b * 16 + h) * 262144;

    // Q B-frags: qf[s] = Q[q][d = 16s + 8hi + j], j=0..7
    bf16x8 qf[8];
    {
        const __hip_bfloat16* qrow = Q + (size_t)(b * SS + q) * 2048 + h * 128;
        #pragma unroll
        for (int s = 0; s < 8; s++)
            qf[s] = ld_frag(qrow + s * 16 + hi * 8);
    }

    // staging: wave w stages K regions (kvt-half w&1, s = 2*(w>>1)+i) and V
    // regions {2w, 2w+1}; contiguous 1KB sources, linear LDS dests.
    const int loff = lane * 8;                               // slot offset
    const size_t kwoff = (size_t)((w & 1) * 4096 + (w >> 1) * 1024) + loff;
    const size_t vwoff = (size_t)(2 * w) * 512 + loff;
    const int kroff = ((w & 1) * 8 + (w >> 1) * 2) * 512 + loff; // K LDS off
    const int vroff = 2 * w * 512 + loff;                        // V LDS off

    float m_i = -INFINITY;   // running max, log2 domain (S * C2LOG)
    float l_i = 0.0f;
    f32x16 acc[4] = {};      // O^T: acc[dt], d = dt*32 + 8*(e>>2) + 4hi + (e&3), col q=l31

    // prologue: stage tile 0 -> buf0, tile 1 -> buf1 (8 loads in flight)
    GLD16(Kfb + kwoff,       &Ktd[kroff]);
    GLD16(Kfb + kwoff + 512, &Ktd[kroff + 512]);
    GLD16(Vfb + vwoff,       &Vsd[vroff]);
    GLD16(Vfb + vwoff + 512, &Vsd[vroff + 512]);
    GLD16(Kfb + 8192 + kwoff,       &Ktd[8192 + kroff]);
    GLD16(Kfb + 8192 + kwoff + 512, &Ktd[8192 + kroff + 512]);
    GLD16(Vfb + 8192 + vwoff,       &Vsd[8192 + vroff]);
    GLD16(Vfb + 8192 + vwoff + 512, &Vsd[8192 + vroff + 512]);
    // pin the qf waitcnt into the prologue (fake use)
    asm volatile("" :: "v"(qf[0]), "v"(qf[1]), "v"(qf[2]), "v"(qf[3]),
                       "v"(qf[4]), "v"(qf[5]), "v"(qf[6]), "v"(qf[7]));

    int cb = 0, sb = 2;   // compute-buffer / stage-buffer (rotating mod 3)
    for (int kt = 0; kt < nbig; kt++) {
        const int kvb = kt * 64;
        const bool active = (kt < my_nt);

        asm volatile("s_waitcnt vmcnt(4)" ::: "memory");  // tile kt landed; kt+1 in flight
        __builtin_amdgcn_s_barrier();   // tile kt visible; buf sb free
        asm volatile("" ::: "memory");

        // ---- stage tile min(kt+2, nbig-1) into buf sb ----
        {
            const size_t soff = (size_t)((kt + 2 < nbig) ? kt + 2 : nbig - 1) * 8192;
            const int sl = sb * 8192;
            GLD16(Kfb + soff + kwoff,       &Ktd[sl + kroff]);
            GLD16(Kfb + soff + kwoff + 512, &Ktd[sl + kroff + 512]);
            GLD16(Vfb + soff + vwoff,       &Vsd[sl + vroff]);
            GLD16(Vfb + soff + vwoff + 512, &Vsd[sl + vroff + 512]);
        }

        if (active) {
            const __hip_bfloat16* kb_base = &Ktd[cb * 8192];
            const __hip_bfloat16* vb_base = &Vsd[cb * 8192];

            // ---- S^T = K * Q^T : 2 kv-blocks x 8 k-steps of 32x32x16 ----
            f32x16 st[2] = {};
            __builtin_amdgcn_s_setprio(1);
            #pragma unroll
            for (int s = 0; s < 8; s++)
                #pragma unroll
                for (int kb = 0; kb < 2; kb++) {
                    bf16x8 kf = ld_frag(kb_base + (kb * 8 + s) * 512 + loff);
                    st[kb] = __builtin_amdgcn_mfma_f32_32x32x16_bf16(
                        kf, qf[s], st[kb], 0, 0, 0);
                }
            __builtin_amdgcn_s_setprio(0);

            // ---- row max; causal cndmask only on the diagonal tile ----
            float tmx;
            if (kvb + 63 > qwb) {            // wave-uniform: diagonal tile
                const int thr = q - kvb - 4 * hi;   // pass iff kb*32 + 8g + r <= thr
                tmx = -INFINITY;
                #pragma unroll
                for (int kb = 0; kb < 2; kb++)
                    #pragma unroll
                    for (int g = 0; g < 4; g++)
                        #pragma unroll
                        for (int r = 0; r < 4; r++) {
                            const int e = g * 4 + r;
                            float v = (kb * 32 + 8 * g + r <= thr) ? st[kb][e] : -INFINITY;
                            st[kb][e] = v;
                            tmx = fmaxf(tmx, v);
                        }
            } else {                          // interior: max3-fusible tree
                tmx = fmaxf(st[0][0], st[0][1]);
                #pragma unroll
                for (int e = 2; e < 16; e += 2)
                    tmx = fmaxf(fmaxf(tmx, st[0][e]), st[0][e + 1]);
                #pragma unroll
                for (int e = 0; e < 16; e += 2)
                    tmx = fmaxf(fmaxf(tmx, st[1][e]), st[1][e + 1]);
            }
            tmx = fmaxf(tmx, __shfl_xor(tmx, 32));
            const float m2x = tmx * C2LOG;

            // ---- online softmax (log2 domain) + T13 defer-max ----
            const bool nosc = __all(m2x <= m_i + 8.0f);
            const float mnew = nosc ? m_i : fmaxf(m_i, m2x);
            float rs = 0.0f;
            #pragma unroll
            for (int kb = 0; kb < 2; kb++)
                #pragma unroll
                for (int e = 0; e < 16; e++) {
                    float pv = exp2f(fmaf(st[kb][e], C2LOG, -mnew));
                    st[kb][e] = pv;
                    rs += pv;
                }
            rs += __shfl_xor(rs, 32);
            if (!nosc) {
                const float alpha = exp2f(m_i - mnew);
                m_i = mnew;
                l_i *= alpha;
                #pragma unroll
                for (int dt = 0; dt < 4; dt++)
                    #pragma unroll
                    for (int e = 0; e < 16; e++)
                        acc[dt][e] *= alpha;
            }
            l_i += rs;

            // ---- P -> bf16 PV B-frags in registers (T12, HW cvt_pk) ----
            uint4 af[4];
            #pragma unroll
            for (int kb = 0; kb < 2; kb++) {
                unsigned int pk[4][2];
                #pragma unroll
                for (int g = 0; g < 4; g++)
                    #pragma unroll
                    for (int i = 0; i < 2; i++)
                        pk[g][i] = cvt_pk_bf16(st[kb][g * 4 + 2 * i],
                                               st[kb][g * 4 + 2 * i + 1]);
                #pragma unroll
                for (int sl = 0; sl < 2; sl++) {
                    uintx2 r0 = __builtin_amdgcn_permlane32_swap(
                        pk[2 * sl][0], pk[2 * sl + 1][0], false, false);
                    uintx2 r1 = __builtin_amdgcn_permlane32_swap(
                        pk[2 * sl][1], pk[2 * sl + 1][1], false, false);
                    af[kb * 2 + sl] = make_uint4(r0[0], r1[0], r0[1], r1[1]);
                }
            }

            // ---- O^T += V^T * P^T : 4 d-tiles x 4 kv-steps ----
            __builtin_amdgcn_s_setprio(1);
            #pragma unroll
            for (int s = 0; s < 4; s++) {
                bf16x8 pf = __builtin_bit_cast(bf16x8, af[s]);
                #pragma unroll
                for (int dt = 0; dt < 4; dt++) {
                    bf16x8 vf = ld_frag(vb_base + (dt * 4 + s) * 512 + loff);
                    acc[dt] = __builtin_amdgcn_mfma_f32_32x32x16_bf16(
                        vf, pf, acc[dt], 0, 0, 0);
                }
            }
            __builtin_amdgcn_s_setprio(0);
        }

        cb = (cb == 2) ? 0 : cb + 1;
        sb = (sb == 2) ? 0 : sb + 1;
    }

    // ---- epilogue: per-lane q = l31, d = dt*32 + 8g + 4hi + r ----
    const float inv_l = 1.0f / l_i;
    __hip_bfloat16* orow = O + (size_t)(b * SS + q) * 2048 + h * 128;
    #pragma unroll
    for (int dt = 0; dt < 4; dt++)
        #pragma unroll
        for (int g = 0; g < 4; g++) {
            uint2 uu;
            uu.x = cvt_pk_bf16(acc[dt][g * 4 + 0] * inv_l, acc[dt][g * 4 + 1] * inv_l);
            uu.y = cvt_pk_bf16(acc[dt][g * 4 + 2] * inv_l, acc[dt][g * 4 + 3] * inv_l);
            *reinterpret_cast<uint2*>(orow + dt * 32 + 8 * g + 4 * hi) = uu;
        }
}

// ---------------------------------------------------------------------------
extern "C" void kernel_launch(void* const* d_in, const int* in_sizes, int n_in,
                              void* d_out, int out_size, void* d_ws, size_t ws_size,
                              hipStream_t stream)
{
    const float* hs       = (const float*)d_in[0];
    const float* w_kv_d   = (const float*)d_in[1];
    const float* w_q_d    = (const float*)d_in[2];
    const float* w_k_u    = (const float*)d_in[3];
    const float* w_q_u    = (const float*)d_in[4];
    const float* w_v_u    = (const float*)d_in[5];
    const float* w_rope_k = (const float*)d_in[6];
    const float* w_rope_q = (const float*)d_in[7];
    const float* w_o      = (const float*)d_in[8];
    float* out = (float*)d_out;

    char* p = (char*)d_ws;
    auto alloc = [&](size_t nelem) {
        __hip_bfloat16* r = (__hip_bfloat16*)p;
        p += nelem * sizeof(__hip_bfloat16);
        return r;
    };
    __hip_bfloat16* hsb  = alloc((size_t)BS * HID);        // 16 MB (reused as attn)
    __hip_bfloat16* qkvd = alloc((size_t)BS * 512);        // 4 MB
    __hip_bfloat16* WT1  = alloc((size_t)1536 * 2048);     // 6 MB
    __hip_bfloat16* WT2  = alloc((size_t)3072 * 256);      // 1.5 MB
    __hip_bfloat16* WT3  = alloc((size_t)2048 * 256);      // 1 MB
    __hip_bfloat16* WTo  = alloc((size_t)2048 * 2048);     // 8 MB
    __hip_bfloat16* Kf   = alloc((size_t)BS * HID);        // 16 MB, fragment-order K
    __hip_bfloat16* Qbuf = alloc((size_t)BS * HID);        // 16 MB
    __hip_bfloat16* Vf   = alloc((size_t)HID * BS);        // 16 MB, fragment-order V
    __hip_bfloat16* attn = hsb;   // hs dead after G1

    dim3 blk(256);

    // 0a. hs -> bf16
    convert_kernel<<<dim3((BS * HID / 8 + 255) / 256), blk, 0, stream>>>(
        hs, hsb, BS * HID / 8);
    // 0b. all weights: transpose + convert to bf16 W^T
    transpose_weights_kernel<<<dim3(8448), blk, 0, stream>>>(
        w_kv_d, w_q_d, w_rope_k, w_k_u, w_v_u, w_q_u, w_rope_q, w_o,
        WT1, WT2, WT3, WTo);

    // G1: [kv_d | q_d | krp] = hsb @ WT1^T  (N=1536, K=2048); krp -> Kf d=64..127
    gemm_bt_kernel<__hip_bfloat16><<<dim3(1536 / 128, BS / 128), blk, 0, stream>>>(
        hsb, 2048, WT1,
        qkvd, 512, 0, 0, 1.0f,
        Kf, 0, 3, 64, 1.0f,
        512, 2048);
    // G2: [k_p | v] = kv_d @ WT2^T  (N=3072, K=256); k_p -> Kf d=0..63, v -> Vf
    gemm_bt_kernel<__hip_bfloat16><<<dim3(3072 / 128, BS / 128), blk, 0, stream>>>(
        qkvd, 512, WT2,
        Kf, 0, 3, 0, 1.0f,
        Vf, 0, 4, 0, 1.0f,
        1024, 256);
    // G3: [q_p | q_rope_pre] = q_d @ WT3^T  (N=2048, K=256)
    gemm_bt_kernel<__hip_bfloat16><<<dim3(2048 / 128, BS / 128), blk, 0, stream>>>(
        qkvd + 256, 512, WT3,
        Qbuf, 2048, 1, 0, 1.0f,
        Qbuf, 2048, 1, 64, 1.0f,
        1024, 256);
    // 4. RoPE in-place (K in Kf layout, Q row-major)
    rope_kernel<<<dim3((BS * NH * 32 + 255) / 256), blk, 0, stream>>>(Kf, Qbuf);
    // 5. flash attention v15 -> attn (XCD-grouped, triple-buffered)
    flash_attn_kernel<<<dim3(8, NH, BB), dim3(512), 0, stream>>>(
        Qbuf, Kf, Vf, attn);
    // G4: out = attn @ WTo^T (fp32 out)
    gemm_bt_kernel<float><<<dim3(2048 / 128, BS / 128), blk, 0, stream>>>(
        attn, 2048, WTo,
        out, 2048, 0, 0, 1.0f,
        out, 2048, 0, 0, 1.0f,
        2048, 2048);
}

// Round 9
// 334.477 us; speedup vs baseline: 1.0349x; 1.0349x over previous
//
#include <hip/hip_runtime.h>
#include <hip/hip_bf16.h>

// Problem constants: B=2, S=2048, HID=2048, H=16, HD=128, HD2=64, LAT=256
#define BB 2
#define SS 2048
#define HID 2048
#define NH 16
#define BS (BB*SS)          // 4096 rows
#define SCALE 0.088388347648318447f   // 1/sqrt(128)
#define C2LOG 0.12751743f              // SCALE * log2(e)

typedef __bf16 bf16x8 __attribute__((ext_vector_type(8)));
typedef float f32x4 __attribute__((ext_vector_type(4)));
typedef float f32x16 __attribute__((ext_vector_type(16)));
typedef unsigned int uintx2 __attribute__((ext_vector_type(2)));

__device__ __forceinline__ bf16x8 ld_frag(const __hip_bfloat16* p) {
    uint4 u = *reinterpret_cast<const uint4*>(p);
    return __builtin_bit_cast(bf16x8, u);
}
// HW packed f32->bf16 convert (RNE). gfx950 has no builtin (m240): inline asm.
__device__ __forceinline__ unsigned int cvt_pk_bf16(float a, float b) {
    unsigned int r;
    asm("v_cvt_pk_bf16_f32 %0, %1, %2" : "=v"(r) : "v"(a), "v"(b));
    return r;
}
__device__ __forceinline__ ushort bf_bits(float v) {
    return (ushort)cvt_pk_bf16(v, v);
}
__device__ __forceinline__ void store_c(__hip_bfloat16* C, size_t idx, float v) {
    *reinterpret_cast<ushort*>(&C[idx]) = bf_bits(v);
}
__device__ __forceinline__ void store_c(float* C, size_t idx, float v) {
    C[idx] = v;
}

// async global->LDS, 16B per lane; lds addr must be wave-uniform base + lane*16
#define GLD16(gp, lp) \
  __builtin_amdgcn_global_load_lds((const __attribute__((address_space(1))) void*)(gp), \
                                   (__attribute__((address_space(3))) void*)(lp), 16, 0, 0)

// ---------------------------------------------------------------------------
// Fragment-order global layouts (v13, kept).
// Kf: element K[b][kv][h][d] ->
//   (b*16+h)*262144 + (kv>>5)*4096 + (d>>4)*512 + ((d>>3)&1)*256 + (kv&31)*8 + (d&7)
// Vf: element V[b][kv][h][d] ->
//   (b*16+h)*262144 + (kv>>6)*8192 + (d>>5)*2048 + ((kv>>4)&3)*512
//   + ((kv>>3)&1)*256 + (d&31)*8 + (kv&7)
// ---------------------------------------------------------------------------

// ---------------------------------------------------------------------------
// fp32 -> bf16 flat convert (hs)
// ---------------------------------------------------------------------------
__global__ __launch_bounds__(256) void convert_kernel(
    const float* __restrict__ src, __hip_bfloat16* __restrict__ dst, int n8)
{
    int i = blockIdx.x * blockDim.x + threadIdx.x;
    if (i >= n8) return;
    float4 a = reinterpret_cast<const float4*>(src)[2 * i];
    float4 b = reinterpret_cast<const float4*>(src)[2 * i + 1];
    uint4 o;
    o.x = cvt_pk_bf16(a.x, a.y);
    o.y = cvt_pk_bf16(a.z, a.w);
    o.z = cvt_pk_bf16(b.x, b.y);
    o.w = cvt_pk_bf16(b.z, b.w);
    reinterpret_cast<uint4*>(dst)[i] = o;
}

// ---------------------------------------------------------------------------
// Fused weight transpose+convert: 8 segments, src fp32 [R][C] -> dst bf16 [C][R]
// ---------------------------------------------------------------------------
__global__ __launch_bounds__(256) void transpose_weights_kernel(
    const float* s0, const float* s1, const float* s2, const float* s3,
    const float* s4, const float* s5, const float* s6, const float* s7,
    __hip_bfloat16* WT1, __hip_bfloat16* WT2, __hip_bfloat16* WT3,
    __hip_bfloat16* WTo)
{
    const float* srcs[8] = { s0, s1, s2, s3, s4, s5, s6, s7 };
    const int Rs[8] = { 2048, 2048, 2048, 256, 256, 256, 256, 2048 };
    const int Cs[8] = { 256, 256, 1024, 1024, 2048, 1024, 1024, 2048 };
    __hip_bfloat16* dsts[8] = {
        WT1, WT1 + (size_t)256 * 2048, WT1 + (size_t)512 * 2048,
        WT2, WT2 + (size_t)1024 * 256,
        WT3, WT3 + (size_t)1024 * 256,
        WTo };
    const int prefix[9] = { 0, 512, 1024, 3072, 3328, 3840, 4096, 4352, 8448 };

    int bid = blockIdx.x;
    int seg = 0;
    #pragma unroll
    for (int i = 0; i < 8; i++) if (bid >= prefix[i + 1]) seg = i + 1;
    int local = bid - prefix[seg];
    int R = Rs[seg], C = Cs[seg];
    int tilesC = C / 32;
    int tr = local / tilesC, tc = local % tilesC;
    int r0 = tr * 32, c0 = tc * 32;
    const float* src = srcs[seg];
    __hip_bfloat16* dst = dsts[seg];

    __shared__ float Ts[32][33];
    int t = threadIdx.x;
    int ty = t >> 5, tx = t & 31;
    #pragma unroll
    for (int k = 0; k < 4; k++) {
        int r = ty + k * 8;
        Ts[r][tx] = src[(size_t)(r0 + r) * C + c0 + tx];
    }
    __syncthreads();
    #pragma unroll
    for (int k = 0; k < 4; k++) {
        int r = ty + k * 8;
        *reinterpret_cast<ushort*>(&dst[(size_t)(c0 + r) * R + r0 + tx]) =
            bf_bits(Ts[tx][r]);
    }
}

// ---------------------------------------------------------------------------
// m97-style GEMM: C = A[M,K] * Bt[N,K]^T, bf16 in, fp32 acc.
// 128x128 tile, BK=32, global_load_lds staging, 4 waves each 64x64.
// + bijective XCD swizzle (T1; all grids here have nwg%8==0).
// Epilogue routing: col < splitN -> (C0,...) else (C1,...). cm = output scale.
//   s64==0: plain col
//   s64==1: col c -> (c>>6)*128 + (c&63) + off (head scatter, row-major)
//   s64==2: transposed store: Cp[c*4096 + row]
//   s64==3: Kf fragment-order scatter; c: h=c>>6, d=off+(c&63); row m: b,kv
//   s64==4: Vf fragment-order scatter; c: h=c>>7, d=c&127;    row m: b,kv
// ---------------------------------------------------------------------------
template <typename TC>
__global__ __launch_bounds__(256) void gemm_bt_kernel(
    const __hip_bfloat16* __restrict__ A, int lda,
    const __hip_bfloat16* __restrict__ Bt,
    TC* __restrict__ C0, int ldc0, int sp0, int off0, float cm0,
    TC* __restrict__ C1, int ldc1, int sp1, int off1, float cm1,
    int splitN, int K)
{
    __shared__ alignas(16) __hip_bfloat16 As[128 * 32];
    __shared__ alignas(16) __hip_bfloat16 Bs[128 * 32];

    // XCD-aware bijective remap (nwg % 8 == 0 for all launches here)
    const int nwg = gridDim.x * gridDim.y;
    int lin = blockIdx.y * gridDim.x + blockIdx.x;
    lin = (lin & 7) * (nwg >> 3) + (lin >> 3);
    const int bn = (lin % gridDim.x) * 128;
    const int bm = (lin / gridDim.x) * 128;

    const int t = threadIdx.x;
    const int w = t >> 6;
    const int lane = t & 63;
    const int l15 = lane & 15;
    const int quad = lane >> 4;
    const int wm = (w & 1) * 64;
    const int wn = (w >> 1) * 64;

    const int srow = lane >> 2;          // 0..15
    const int skcol = (lane & 3) * 8;    // 0,8,16,24

    f32x4 acc[4][4] = {};

    for (int k0 = 0; k0 < K; k0 += 32) {
        __syncthreads();
        #pragma unroll
        for (int i = 0; i < 2; i++) {
            int r = w * 32 + i * 16 + srow;
            GLD16(A + (size_t)(bm + r) * lda + k0 + skcol, &As[r * 32 + skcol]);
            GLD16(Bt + (size_t)(bn + r) * K + k0 + skcol, &Bs[r * 32 + skcol]);
        }
        __syncthreads();

        bf16x8 af[4], bf[4];
        #pragma unroll
        for (int mt = 0; mt < 4; mt++)
            af[mt] = ld_frag(&As[(wm + mt * 16 + l15) * 32 + quad * 8]);
        #pragma unroll
        for (int nt = 0; nt < 4; nt++)
            bf[nt] = ld_frag(&Bs[(wn + nt * 16 + l15) * 32 + quad * 8]);
        #pragma unroll
        for (int mt = 0; mt < 4; mt++)
            #pragma unroll
            for (int nt = 0; nt < 4; nt++)
                acc[mt][nt] = __builtin_amdgcn_mfma_f32_16x16x32_bf16(
                    af[mt], bf[nt], acc[mt][nt], 0, 0, 0);
    }

    #pragma unroll
    for (int nt = 0; nt < 4; nt++) {
        int col = bn + wn + nt * 16 + l15;
        TC* Cp; int c, ld, s64, off; float cm;
        if (col < splitN) { Cp = C0; c = col; ld = ldc0; s64 = sp0; off = off0; cm = cm0; }
        else { Cp = C1; c = col - splitN; ld = ldc1; s64 = sp1; off = off1; cm = cm1; }
        if (s64 == 2) {
            #pragma unroll
            for (int mt = 0; mt < 4; mt++) {
                int row0 = bm + wm + mt * 16 + quad * 4;
                #pragma unroll
                for (int r = 0; r < 4; r++)
                    store_c(Cp, (size_t)c * 4096 + row0 + r, acc[mt][nt][r] * cm);
            }
        } else if (s64 == 3) {
            const int hh = c >> 6, d = off + (c & 63);
            const size_t dbase = (size_t)(d >> 4) * 512
                               + (size_t)((d >> 3) & 1) * 256 + (d & 7);
            #pragma unroll
            for (int mt = 0; mt < 4; mt++) {
                #pragma unroll
                for (int r = 0; r < 4; r++) {
                    int m = bm + wm + mt * 16 + quad * 4 + r;
                    int bb2 = m >> 11, kv = m & 2047;
                    size_t idx = (size_t)(bb2 * 16 + hh) * 262144
                               + (size_t)(kv >> 5) * 4096 + dbase
                               + (size_t)(kv & 31) * 8;
                    store_c(Cp, idx, acc[mt][nt][r] * cm);
                }
            }
        } else if (s64 == 4) {
            const int hh = c >> 7, d = c & 127;
            const size_t dbase = (size_t)(d >> 5) * 2048 + (size_t)(d & 31) * 8;
            #pragma unroll
            for (int mt = 0; mt < 4; mt++) {
                #pragma unroll
                for (int r = 0; r < 4; r++) {
                    int m = bm + wm + mt * 16 + quad * 4 + r;
                    int bb2 = m >> 11, kv = m & 2047;
                    size_t idx = (size_t)(bb2 * 16 + hh) * 262144
                               + (size_t)(kv >> 6) * 8192 + dbase
                               + (size_t)((kv >> 4) & 3) * 512
                               + (size_t)((kv >> 3) & 1) * 256 + (kv & 7);
                    store_c(Cp, idx, acc[mt][nt][r] * cm);
                }
            }
        } else {
            int oc = s64 ? ((c >> 6) * 128 + (c & 63) + off) : c;
            #pragma unroll
            for (int mt = 0; mt < 4; mt++) {
                #pragma unroll
                for (int r = 0; r < 4; r++) {
                    int row = bm + wm + mt * 16 + quad * 4 + r;
                    store_c(Cp, (size_t)row * ld + oc, acc[mt][nt][r] * cm);
                }
            }
        }
    }
}

// ---------------------------------------------------------------------------
// RoPE in-place: K in Kf fragment-order layout, Q in row-major Qbuf.
// Pair (d1=64+i, d2=96+i): in Kf, d2 is exactly +2 regions = +1024 elems.
// ---------------------------------------------------------------------------
__global__ __launch_bounds__(256) void rope_kernel(
    __hip_bfloat16* __restrict__ Kf, __hip_bfloat16* __restrict__ Qb)
{
    int idx = blockIdx.x * blockDim.x + threadIdx.x;
    if (idx >= BS * NH * 32) return;
    int i = idx & 31;
    int h = (idx >> 5) & 15;
    int row = idx >> 9;
    int s = row & (SS - 1);
    int b = row >> 11;

    float inv = exp2f(-(float)i * 0.4152410118609203f);  // 10000^(-i/32)
    float ang = (float)s * inv;
    float sn = sinf(ang), cs = cosf(ang);

    {   // K (Kf layout)
        size_t kaddr = ((size_t)(b * 16 + h) * 64 + (s >> 5)) * 4096
                     + (size_t)(4 + (i >> 4)) * 512
                     + (size_t)(((i >> 3) & 1) * 32 + (s & 31)) * 8 + (i & 7);
        float x1 = __bfloat162float(Kf[kaddr]);
        float x2 = __bfloat162float(Kf[kaddr + 1024]);
        *reinterpret_cast<ushort*>(&Kf[kaddr])        = bf_bits(x1 * cs - x2 * sn);
        *reinterpret_cast<ushort*>(&Kf[kaddr + 1024]) = bf_bits(x1 * sn + x2 * cs);
    }
    {   // Q (row-major)
        size_t obase = (size_t)row * 2048 + h * 128 + 64 + i;
        float x1 = __bfloat162float(Qb[obase]);
        float x2 = __bfloat162float(Qb[obase + 32]);
        *reinterpret_cast<ushort*>(&Qb[obase])      = bf_bits(x1 * cs - x2 * sn);
        *reinterpret_cast<ushort*>(&Qb[obase + 32]) = bf_bits(x1 * sn + x2 * cs);
    }
}

// ---------------------------------------------------------------------------
// Flash attention v16 = v14's proven pipeline (dbuf K+V, stage-after-barrier,
// vmcnt(0) referencing loads issued a full iteration earlier => near-zero
// drain; 69.1us measured) + v15's XCD (b,h)-grouped decode (FETCH 110->24.6MB
// measured). r8 unbundle: the triple-buffer/vmcnt(4) rework caused the v15
// regression (compiler-inserted conservative waits defeat counted vmcnt over
// gld_lds->ds_read hazards); the grouping itself was a pure win. LDS back to
// 64KB.
// ---------------------------------------------------------------------------
__global__ __launch_bounds__(512) void flash_attn_kernel(
    const __hip_bfloat16* __restrict__ Q,
    const __hip_bfloat16* __restrict__ Kf,
    const __hip_bfloat16* __restrict__ Vf,
    __hip_bfloat16* __restrict__ O)
{
    __shared__ alignas(16) __hip_bfloat16 Ktd[2 * 16 * 512];  // [par][region][slot]
    __shared__ alignas(16) __hip_bfloat16 Vsd[2 * 16 * 512];

    // XCD-grouped decode: same-(b,h) blocks share blockIdx.x -> same XCD,
    // tile-synchronized L2 reuse; long/short blocks mixed across XCDs.
    const int p = blockIdx.y & 7;                     // pair index 0..7
    const int h = blockIdx.x + 8 * (blockIdx.y >> 3); // head 0..15
    const int b = blockIdx.z;
    const int t = threadIdx.x;
    const int w = t >> 6;                // 0..7
    const int lane = t & 63;
    const int l31 = lane & 31;
    const int hi = lane >> 5;

    const int qt = (w < 4) ? (15 - p) : p;   // this wave's q-tile
    const int wq = w & 3;
    const int qwb = qt * 128 + wq * 32;      // wave's q base (32 rows)
    const int q = qwb + l31;                 // this lane's q row
    const int my_nt = 2 * qt + 1 + (wq >> 1);// kv tiles this wave needs
    const int nbig = 2 * (15 - p) + 2;       // shared loop length

    const __hip_bfloat16* Kfb = Kf + (size_t)(b * 16 + h) * 262144;
    const __hip_bfloat16* Vfb = Vf + (size_t)(b * 16 + h) * 262144;

    // Q B-frags: qf[s] = Q[q][d = 16s + 8hi + j], j=0..7
    bf16x8 qf[8];
    {
        const __hip_bfloat16* qrow = Q + (size_t)(b * SS + q) * 2048 + h * 128;
        #pragma unroll
        for (int s = 0; s < 8; s++)
            qf[s] = ld_frag(qrow + s * 16 + hi * 8);
    }

    // staging: wave w stages K regions (kvt-half w&1, s = 2*(w>>1)+i) and V
    // regions {2w, 2w+1}. Running global pointers advance +8192 elems/tile.
    const int kreg = (w & 1) * 8 + (w >> 1) * 2;   // K LDS region base
    const int loff = lane * 8;                     // slot offset (elements)
    const __hip_bfloat16* kp = Kfb + (size_t)((w & 1) * 4096 + (w >> 1) * 1024) + loff;
    const __hip_bfloat16* vp = Vfb + (size_t)(2 * w) * 512 + loff;
    __hip_bfloat16* kd[2] = { &Ktd[kreg * 512 + loff], &Ktd[8192 + kreg * 512 + loff] };
    __hip_bfloat16* vd[2] = { &Vsd[2 * w * 512 + loff], &Vsd[8192 + 2 * w * 512 + loff] };

    float m_i = -INFINITY;   // running max, log2 domain (S * C2LOG)
    float l_i = 0.0f;
    f32x16 acc[4] = {};      // O^T: acc[dt], d = dt*32 + 8*(e>>2) + 4hi + (e&3), col q=l31

    // prologue: stage tile 0 (K and V) into par 0
    GLD16(kp, kd[0]);
    GLD16(kp + 512, kd[0] + 512);
    GLD16(vp, vd[0]);
    GLD16(vp + 512, vd[0] + 512);
    kp += 8192; vp += 8192;
    // pin the qf waitcnt into the prologue (fake use)
    asm volatile("" :: "v"(qf[0]), "v"(qf[1]), "v"(qf[2]), "v"(qf[3]),
                       "v"(qf[4]), "v"(qf[5]), "v"(qf[6]), "v"(qf[7]));

    for (int kt = 0; kt < nbig; kt++) {
        const int kvb = kt * 64;
        const int par = kt & 1;
        const bool active = (kt < my_nt);

        asm volatile("s_waitcnt vmcnt(0)" ::: "memory");  // my tile-kt loads done
        __builtin_amdgcn_s_barrier();   // all tile-kt loads visible; par^1 free
        asm volatile("" ::: "memory");

        // ---- stage tile kt+1 into par^1 (pointer held on last tiles) ----
        {
            const int pn = par ^ 1;
            GLD16(kp, kd[pn]);
            GLD16(kp + 512, kd[pn] + 512);
            GLD16(vp, vd[pn]);
            GLD16(vp + 512, vd[pn] + 512);
            if (kt + 2 < nbig) { kp += 8192; vp += 8192; }
        }

        if (active) {
            const __hip_bfloat16* kb_base = &Ktd[par * 8192];
            const __hip_bfloat16* vb_base = &Vsd[par * 8192];

            // ---- S^T = K * Q^T : 2 kv-blocks x 8 k-steps of 32x32x16 ----
            f32x16 st[2] = {};
            __builtin_amdgcn_s_setprio(1);
            #pragma unroll
            for (int s = 0; s < 8; s++)
                #pragma unroll
                for (int kb = 0; kb < 2; kb++) {
                    bf16x8 kf = ld_frag(kb_base + (kb * 8 + s) * 512 + loff);
                    st[kb] = __builtin_amdgcn_mfma_f32_32x32x16_bf16(
                        kf, qf[s], st[kb], 0, 0, 0);
                }
            __builtin_amdgcn_s_setprio(0);

            // ---- row max; causal cndmask only on the diagonal tile ----
            float tmx;
            if (kvb + 63 > qwb) {            // wave-uniform: diagonal tile
                const int thr = q - kvb - 4 * hi;   // pass iff kb*32 + 8g + r <= thr
                tmx = -INFINITY;
                #pragma unroll
                for (int kb = 0; kb < 2; kb++)
                    #pragma unroll
                    for (int g = 0; g < 4; g++)
                        #pragma unroll
                        for (int r = 0; r < 4; r++) {
                            const int e = g * 4 + r;
                            float v = (kb * 32 + 8 * g + r <= thr) ? st[kb][e] : -INFINITY;
                            st[kb][e] = v;
                            tmx = fmaxf(tmx, v);
                        }
            } else {                          // interior: max3-fusible tree
                tmx = fmaxf(st[0][0], st[0][1]);
                #pragma unroll
                for (int e = 2; e < 16; e += 2)
                    tmx = fmaxf(fmaxf(tmx, st[0][e]), st[0][e + 1]);
                #pragma unroll
                for (int e = 0; e < 16; e += 2)
                    tmx = fmaxf(fmaxf(tmx, st[1][e]), st[1][e + 1]);
            }
            tmx = fmaxf(tmx, __shfl_xor(tmx, 32));
            const float m2x = tmx * C2LOG;

            // ---- online softmax (log2 domain) + T13 defer-max ----
            const bool nosc = __all(m2x <= m_i + 8.0f);
            const float mnew = nosc ? m_i : fmaxf(m_i, m2x);
            float rs = 0.0f;
            #pragma unroll
            for (int kb = 0; kb < 2; kb++)
                #pragma unroll
                for (int e = 0; e < 16; e++) {
                    float pv = exp2f(fmaf(st[kb][e], C2LOG, -mnew));
                    st[kb][e] = pv;
                    rs += pv;
                }
            rs += __shfl_xor(rs, 32);
            if (!nosc) {
                const float alpha = exp2f(m_i - mnew);
                m_i = mnew;
                l_i *= alpha;
                #pragma unroll
                for (int dt = 0; dt < 4; dt++)
                    #pragma unroll
                    for (int e = 0; e < 16; e++)
                        acc[dt][e] *= alpha;
            }
            l_i += rs;

            // ---- P -> bf16 PV B-frags in registers (T12, HW cvt_pk) ----
            uint4 af[4];
            #pragma unroll
            for (int kb = 0; kb < 2; kb++) {
                unsigned int pk[4][2];
                #pragma unroll
                for (int g = 0; g < 4; g++)
                    #pragma unroll
                    for (int i = 0; i < 2; i++)
                        pk[g][i] = cvt_pk_bf16(st[kb][g * 4 + 2 * i],
                                               st[kb][g * 4 + 2 * i + 1]);
                #pragma unroll
                for (int sl = 0; sl < 2; sl++) {
                    uintx2 r0 = __builtin_amdgcn_permlane32_swap(
                        pk[2 * sl][0], pk[2 * sl + 1][0], false, false);
                    uintx2 r1 = __builtin_amdgcn_permlane32_swap(
                        pk[2 * sl][1], pk[2 * sl + 1][1], false, false);
                    af[kb * 2 + sl] = make_uint4(r0[0], r1[0], r0[1], r1[1]);
                }
            }

            // ---- O^T += V^T * P^T : 4 d-tiles x 4 kv-steps ----
            __builtin_amdgcn_s_setprio(1);
            #pragma unroll
            for (int s = 0; s < 4; s++) {
                bf16x8 pf = __builtin_bit_cast(bf16x8, af[s]);
                #pragma unroll
                for (int dt = 0; dt < 4; dt++) {
                    bf16x8 vf = ld_frag(vb_base + (dt * 4 + s) * 512 + loff);
                    acc[dt] = __builtin_amdgcn_mfma_f32_32x32x16_bf16(
                        vf, pf, acc[dt], 0, 0, 0);
                }
            }
            __builtin_amdgcn_s_setprio(0);
        }
    }

    // ---- epilogue: per-lane q = l31, d = dt*32 + 8g + 4hi + r ----
    const float inv_l = 1.0f / l_i;
    __hip_bfloat16* orow = O + (size_t)(b * SS + q) * 2048 + h * 128;
    #pragma unroll
    for (int dt = 0; dt < 4; dt++)
        #pragma unroll
        for (int g = 0; g < 4; g++) {
            uint2 uu;
            uu.x = cvt_pk_bf16(acc[dt][g * 4 + 0] * inv_l, acc[dt][g * 4 + 1] * inv_l);
            uu.y = cvt_pk_bf16(acc[dt][g * 4 + 2] * inv_l, acc[dt][g * 4 + 3] * inv_l);
            *reinterpret_cast<uint2*>(orow + dt * 32 + 8 * g + 4 * hi) = uu;
        }
}

// ---------------------------------------------------------------------------
extern "C" void kernel_launch(void* const* d_in, const int* in_sizes, int n_in,
                              void* d_out, int out_size, void* d_ws, size_t ws_size,
                              hipStream_t stream)
{
    const float* hs       = (const float*)d_in[0];
    const float* w_kv_d   = (const float*)d_in[1];
    const float* w_q_d    = (const float*)d_in[2];
    const float* w_k_u    = (const float*)d_in[3];
    const float* w_q_u    = (const float*)d_in[4];
    const float* w_v_u    = (const float*)d_in[5];
    const float* w_rope_k = (const float*)d_in[6];
    const float* w_rope_q = (const float*)d_in[7];
    const float* w_o      = (const float*)d_in[8];
    float* out = (float*)d_out;

    char* p = (char*)d_ws;
    auto alloc = [&](size_t nelem) {
        __hip_bfloat16* r = (__hip_bfloat16*)p;
        p += nelem * sizeof(__hip_bfloat16);
        return r;
    };
    __hip_bfloat16* hsb  = alloc((size_t)BS * HID);        // 16 MB (reused as attn)
    __hip_bfloat16* qkvd = alloc((size_t)BS * 512);        // 4 MB
    __hip_bfloat16* WT1  = alloc((size_t)1536 * 2048);     // 6 MB
    __hip_bfloat16* WT2  = alloc((size_t)3072 * 256);      // 1.5 MB
    __hip_bfloat16* WT3  = alloc((size_t)2048 * 256);      // 1 MB
    __hip_bfloat16* WTo  = alloc((size_t)2048 * 2048);     // 8 MB
    __hip_bfloat16* Kf   = alloc((size_t)BS * HID);        // 16 MB, fragment-order K
    __hip_bfloat16* Qbuf = alloc((size_t)BS * HID);        // 16 MB
    __hip_bfloat16* Vf   = alloc((size_t)HID * BS);        // 16 MB, fragment-order V
    __hip_bfloat16* attn = hsb;   // hs dead after G1

    dim3 blk(256);

    // 0a. hs -> bf16
    convert_kernel<<<dim3((BS * HID / 8 + 255) / 256), blk, 0, stream>>>(
        hs, hsb, BS * HID / 8);
    // 0b. all weights: transpose + convert to bf16 W^T
    transpose_weights_kernel<<<dim3(8448), blk, 0, stream>>>(
        w_kv_d, w_q_d, w_rope_k, w_k_u, w_v_u, w_q_u, w_rope_q, w_o,
        WT1, WT2, WT3, WTo);

    // G1: [kv_d | q_d | krp] = hsb @ WT1^T  (N=1536, K=2048); krp -> Kf d=64..127
    gemm_bt_kernel<__hip_bfloat16><<<dim3(1536 / 128, BS / 128), blk, 0, stream>>>(
        hsb, 2048, WT1,
        qkvd, 512, 0, 0, 1.0f,
        Kf, 0, 3, 64, 1.0f,
        512, 2048);
    // G2: [k_p | v] = kv_d @ WT2^T  (N=3072, K=256); k_p -> Kf d=0..63, v -> Vf
    gemm_bt_kernel<__hip_bfloat16><<<dim3(3072 / 128, BS / 128), blk, 0, stream>>>(
        qkvd, 512, WT2,
        Kf, 0, 3, 0, 1.0f,
        Vf, 0, 4, 0, 1.0f,
        1024, 256);
    // G3: [q_p | q_rope_pre] = q_d @ WT3^T  (N=2048, K=256)
    gemm_bt_kernel<__hip_bfloat16><<<dim3(2048 / 128, BS / 128), blk, 0, stream>>>(
        qkvd + 256, 512, WT3,
        Qbuf, 2048, 1, 0, 1.0f,
        Qbuf, 2048, 1, 64, 1.0f,
        1024, 256);
    // 4. RoPE in-place (K in Kf layout, Q row-major)
    rope_kernel<<<dim3((BS * NH * 32 + 255) / 256), blk, 0, stream>>>(Kf, Qbuf);
    // 5. flash attention v16 -> attn (v14 pipeline + XCD grouping)
    flash_attn_kernel<<<dim3(8, NH, BB), dim3(512), 0, stream>>>(
        Qbuf, Kf, Vf, attn);
    // G4: out = attn @ WTo^T (fp32 out)
    gemm_bt_kernel<float><<<dim3(2048 / 128, BS / 128), blk, 0, stream>>>(
        attn, 2048, WTo,
        out, 2048, 0, 0, 1.0f,
        out, 2048, 0, 0, 1.0f,
        2048, 2048);
}

// Round 10
// 330.347 us; speedup vs baseline: 1.0479x; 1.0125x over previous
//
#include <hip/hip_runtime.h>
#include <hip/hip_bf16.h>

// Problem constants: B=2, S=2048, HID=2048, H=16, HD=128, HD2=64, LAT=256
#define BB 2
#define SS 2048
#define HID 2048
#define NH 16
#define BS (BB*SS)          // 4096 rows
#define SCALE 0.088388347648318447f   // 1/sqrt(128)
#define C2LOG 0.12751743f              // SCALE * log2(e)

typedef __bf16 bf16x8 __attribute__((ext_vector_type(8)));
typedef float f32x4 __attribute__((ext_vector_type(4)));
typedef float f32x16 __attribute__((ext_vector_type(16)));
typedef unsigned int uintx2 __attribute__((ext_vector_type(2)));

__device__ __forceinline__ bf16x8 ld_frag(const __hip_bfloat16* p) {
    uint4 u = *reinterpret_cast<const uint4*>(p);
    return __builtin_bit_cast(bf16x8, u);
}
// HW packed f32->bf16 convert (RNE). gfx950 has no builtin (m240): inline asm.
__device__ __forceinline__ unsigned int cvt_pk_bf16(float a, float b) {
    unsigned int r;
    asm("v_cvt_pk_bf16_f32 %0, %1, %2" : "=v"(r) : "v"(a), "v"(b));
    return r;
}
__device__ __forceinline__ ushort bf_bits(float v) {
    return (ushort)cvt_pk_bf16(v, v);
}
__device__ __forceinline__ void store_c(__hip_bfloat16* C, size_t idx, float v) {
    *reinterpret_cast<ushort*>(&C[idx]) = bf_bits(v);
}
__device__ __forceinline__ void store_c(float* C, size_t idx, float v) {
    C[idx] = v;
}

// async global->LDS, 16B per lane; lds addr must be wave-uniform base + lane*16
#define GLD16(gp, lp) \
  __builtin_amdgcn_global_load_lds((const __attribute__((address_space(1))) void*)(gp), \
                                   (__attribute__((address_space(3))) void*)(lp), 16, 0, 0)

// ---------------------------------------------------------------------------
// Fragment-order global layouts (v13, kept).
// Kf: element K[b][kv][h][d] ->
//   (b*16+h)*262144 + (kv>>5)*4096 + (d>>4)*512 + ((d>>3)&1)*256 + (kv&31)*8 + (d&7)
// Vf: element V[b][kv][h][d] ->
//   (b*16+h)*262144 + (kv>>6)*8192 + (d>>5)*2048 + ((kv>>4)&3)*512
//   + ((kv>>3)&1)*256 + (d&31)*8 + (kv&7)
// ---------------------------------------------------------------------------

// ---------------------------------------------------------------------------
// fp32 -> bf16 flat convert (hs)
// ---------------------------------------------------------------------------
__global__ __launch_bounds__(256) void convert_kernel(
    const float* __restrict__ src, __hip_bfloat16* __restrict__ dst, int n8)
{
    int i = blockIdx.x * blockDim.x + threadIdx.x;
    if (i >= n8) return;
    float4 a = reinterpret_cast<const float4*>(src)[2 * i];
    float4 b = reinterpret_cast<const float4*>(src)[2 * i + 1];
    uint4 o;
    o.x = cvt_pk_bf16(a.x, a.y);
    o.y = cvt_pk_bf16(a.z, a.w);
    o.z = cvt_pk_bf16(b.x, b.y);
    o.w = cvt_pk_bf16(b.z, b.w);
    reinterpret_cast<uint4*>(dst)[i] = o;
}

// ---------------------------------------------------------------------------
// Fused weight transpose+convert: 8 segments, src fp32 [R][C] -> dst bf16 [C][R]
// ---------------------------------------------------------------------------
__global__ __launch_bounds__(256) void transpose_weights_kernel(
    const float* s0, const float* s1, const float* s2, const float* s3,
    const float* s4, const float* s5, const float* s6, const float* s7,
    __hip_bfloat16* WT1, __hip_bfloat16* WT2, __hip_bfloat16* WT3,
    __hip_bfloat16* WTo)
{
    const float* srcs[8] = { s0, s1, s2, s3, s4, s5, s6, s7 };
    const int Rs[8] = { 2048, 2048, 2048, 256, 256, 256, 256, 2048 };
    const int Cs[8] = { 256, 256, 1024, 1024, 2048, 1024, 1024, 2048 };
    __hip_bfloat16* dsts[8] = {
        WT1, WT1 + (size_t)256 * 2048, WT1 + (size_t)512 * 2048,
        WT2, WT2 + (size_t)1024 * 256,
        WT3, WT3 + (size_t)1024 * 256,
        WTo };
    const int prefix[9] = { 0, 512, 1024, 3072, 3328, 3840, 4096, 4352, 8448 };

    int bid = blockIdx.x;
    int seg = 0;
    #pragma unroll
    for (int i = 0; i < 8; i++) if (bid >= prefix[i + 1]) seg = i + 1;
    int local = bid - prefix[seg];
    int R = Rs[seg], C = Cs[seg];
    int tilesC = C / 32;
    int tr = local / tilesC, tc = local % tilesC;
    int r0 = tr * 32, c0 = tc * 32;
    const float* src = srcs[seg];
    __hip_bfloat16* dst = dsts[seg];

    __shared__ float Ts[32][33];
    int t = threadIdx.x;
    int ty = t >> 5, tx = t & 31;
    #pragma unroll
    for (int k = 0; k < 4; k++) {
        int r = ty + k * 8;
        Ts[r][tx] = src[(size_t)(r0 + r) * C + c0 + tx];
    }
    __syncthreads();
    #pragma unroll
    for (int k = 0; k < 4; k++) {
        int r = ty + k * 8;
        *reinterpret_cast<ushort*>(&dst[(size_t)(c0 + r) * R + r0 + tx]) =
            bf_bits(Ts[tx][r]);
    }
}

// ---------------------------------------------------------------------------
// m97-style GEMM: C = A[M,K] * Bt[N,K]^T, bf16 in, fp32 acc.
// 128x128 tile, BK=32, global_load_lds staging, 4 waves each 64x64.
// + bijective XCD swizzle (T1; all grids here have nwg%8==0).
// Epilogue routing: col < splitN -> (C0,...) else (C1,...). cm = output scale.
//   s64==0: plain col
//   s64==1: col c -> (c>>6)*128 + (c&63) + off (head scatter, row-major)
//   s64==2: transposed store: Cp[c*4096 + row]
//   s64==3: Kf fragment-order scatter; c: h=c>>6, d=off+(c&63); row m: b,kv
//   s64==4: Vf fragment-order scatter; c: h=c>>7, d=c&127;    row m: b,kv
// ---------------------------------------------------------------------------
template <typename TC>
__global__ __launch_bounds__(256) void gemm_bt_kernel(
    const __hip_bfloat16* __restrict__ A, int lda,
    const __hip_bfloat16* __restrict__ Bt,
    TC* __restrict__ C0, int ldc0, int sp0, int off0, float cm0,
    TC* __restrict__ C1, int ldc1, int sp1, int off1, float cm1,
    int splitN, int K)
{
    __shared__ alignas(16) __hip_bfloat16 As[128 * 32];
    __shared__ alignas(16) __hip_bfloat16 Bs[128 * 32];

    // XCD-aware bijective remap (nwg % 8 == 0 for all launches here)
    const int nwg = gridDim.x * gridDim.y;
    int lin = blockIdx.y * gridDim.x + blockIdx.x;
    lin = (lin & 7) * (nwg >> 3) + (lin >> 3);
    const int bn = (lin % gridDim.x) * 128;
    const int bm = (lin / gridDim.x) * 128;

    const int t = threadIdx.x;
    const int w = t >> 6;
    const int lane = t & 63;
    const int l15 = lane & 15;
    const int quad = lane >> 4;
    const int wm = (w & 1) * 64;
    const int wn = (w >> 1) * 64;

    const int srow = lane >> 2;          // 0..15
    const int skcol = (lane & 3) * 8;    // 0,8,16,24

    f32x4 acc[4][4] = {};

    for (int k0 = 0; k0 < K; k0 += 32) {
        __syncthreads();
        #pragma unroll
        for (int i = 0; i < 2; i++) {
            int r = w * 32 + i * 16 + srow;
            GLD16(A + (size_t)(bm + r) * lda + k0 + skcol, &As[r * 32 + skcol]);
            GLD16(Bt + (size_t)(bn + r) * K + k0 + skcol, &Bs[r * 32 + skcol]);
        }
        __syncthreads();

        bf16x8 af[4], bf[4];
        #pragma unroll
        for (int mt = 0; mt < 4; mt++)
            af[mt] = ld_frag(&As[(wm + mt * 16 + l15) * 32 + quad * 8]);
        #pragma unroll
        for (int nt = 0; nt < 4; nt++)
            bf[nt] = ld_frag(&Bs[(wn + nt * 16 + l15) * 32 + quad * 8]);
        #pragma unroll
        for (int mt = 0; mt < 4; mt++)
            #pragma unroll
            for (int nt = 0; nt < 4; nt++)
                acc[mt][nt] = __builtin_amdgcn_mfma_f32_16x16x32_bf16(
                    af[mt], bf[nt], acc[mt][nt], 0, 0, 0);
    }

    #pragma unroll
    for (int nt = 0; nt < 4; nt++) {
        int col = bn + wn + nt * 16 + l15;
        TC* Cp; int c, ld, s64, off; float cm;
        if (col < splitN) { Cp = C0; c = col; ld = ldc0; s64 = sp0; off = off0; cm = cm0; }
        else { Cp = C1; c = col - splitN; ld = ldc1; s64 = sp1; off = off1; cm = cm1; }
        if (s64 == 2) {
            #pragma unroll
            for (int mt = 0; mt < 4; mt++) {
                int row0 = bm + wm + mt * 16 + quad * 4;
                #pragma unroll
                for (int r = 0; r < 4; r++)
                    store_c(Cp, (size_t)c * 4096 + row0 + r, acc[mt][nt][r] * cm);
            }
        } else if (s64 == 3) {
            const int hh = c >> 6, d = off + (c & 63);
            const size_t dbase = (size_t)(d >> 4) * 512
                               + (size_t)((d >> 3) & 1) * 256 + (d & 7);
            #pragma unroll
            for (int mt = 0; mt < 4; mt++) {
                #pragma unroll
                for (int r = 0; r < 4; r++) {
                    int m = bm + wm + mt * 16 + quad * 4 + r;
                    int bb2 = m >> 11, kv = m & 2047;
                    size_t idx = (size_t)(bb2 * 16 + hh) * 262144
                               + (size_t)(kv >> 5) * 4096 + dbase
                               + (size_t)(kv & 31) * 8;
                    store_c(Cp, idx, acc[mt][nt][r] * cm);
                }
            }
        } else if (s64 == 4) {
            const int hh = c >> 7, d = c & 127;
            const size_t dbase = (size_t)(d >> 5) * 2048 + (size_t)(d & 31) * 8;
            #pragma unroll
            for (int mt = 0; mt < 4; mt++) {
                #pragma unroll
                for (int r = 0; r < 4; r++) {
                    int m = bm + wm + mt * 16 + quad * 4 + r;
                    int bb2 = m >> 11, kv = m & 2047;
                    size_t idx = (size_t)(bb2 * 16 + hh) * 262144
                               + (size_t)(kv >> 6) * 8192 + dbase
                               + (size_t)((kv >> 4) & 3) * 512
                               + (size_t)((kv >> 3) & 1) * 256 + (kv & 7);
                    store_c(Cp, idx, acc[mt][nt][r] * cm);
                }
            }
        } else {
            int oc = s64 ? ((c >> 6) * 128 + (c & 63) + off) : c;
            #pragma unroll
            for (int mt = 0; mt < 4; mt++) {
                #pragma unroll
                for (int r = 0; r < 4; r++) {
                    int row = bm + wm + mt * 16 + quad * 4 + r;
                    store_c(Cp, (size_t)row * ld + oc, acc[mt][nt][r] * cm);
                }
            }
        }
    }
}

// ---------------------------------------------------------------------------
// RoPE in-place: K in Kf fragment-order layout, Q in row-major Qbuf.
// Pair (d1=64+i, d2=96+i): in Kf, d2 is exactly +2 regions = +1024 elems.
// ---------------------------------------------------------------------------
__global__ __launch_bounds__(256) void rope_kernel(
    __hip_bfloat16* __restrict__ Kf, __hip_bfloat16* __restrict__ Qb)
{
    int idx = blockIdx.x * blockDim.x + threadIdx.x;
    if (idx >= BS * NH * 32) return;
    int i = idx & 31;
    int h = (idx >> 5) & 15;
    int row = idx >> 9;
    int s = row & (SS - 1);
    int b = row >> 11;

    float inv = exp2f(-(float)i * 0.4152410118609203f);  // 10000^(-i/32)
    float ang = (float)s * inv;
    float sn = sinf(ang), cs = cosf(ang);

    {   // K (Kf layout)
        size_t kaddr = ((size_t)(b * 16 + h) * 64 + (s >> 5)) * 4096
                     + (size_t)(4 + (i >> 4)) * 512
                     + (size_t)(((i >> 3) & 1) * 32 + (s & 31)) * 8 + (i & 7);
        float x1 = __bfloat162float(Kf[kaddr]);
        float x2 = __bfloat162float(Kf[kaddr + 1024]);
        *reinterpret_cast<ushort*>(&Kf[kaddr])        = bf_bits(x1 * cs - x2 * sn);
        *reinterpret_cast<ushort*>(&Kf[kaddr + 1024]) = bf_bits(x1 * sn + x2 * cs);
    }
    {   // Q (row-major)
        size_t obase = (size_t)row * 2048 + h * 128 + 64 + i;
        float x1 = __bfloat162float(Qb[obase]);
        float x2 = __bfloat162float(Qb[obase + 32]);
        *reinterpret_cast<ushort*>(&Qb[obase])      = bf_bits(x1 * cs - x2 * sn);
        *reinterpret_cast<ushort*>(&Qb[obase + 32]) = bf_bits(x1 * sn + x2 * cs);
    }
}

// ---------------------------------------------------------------------------
// Flash attention v17: LDS tier DELETED — direct global->register fragment
// loads.
// r9 evidence: v16 (L2-resident staging, FETCH 24.6MB, conflicts 0) stayed at
// 68.8us == v14 -> staging latency was NOT the binder. Budget close: 8 waves
// x 32KB LDS fragment reads = 256KB/CU/iter ~ 3000 cyc at 85 B/cyc b128 --
// the LDS read pipe was the wall, and LDS staging is 8x-redundant by
// construction (stage once, read 8x).
// v17: K/V are fragment-ordered in GLOBAL (v13) and L2-resident (v15/16
// grouping), so each wave loads fragments straight to registers: contiguous
// 1KB per region, lane l reads region*1KB + l*16 (coalesced). No LDS, no
// barriers, no vmcnt, no staging; waves loop only their own causal range.
// L2 redundancy (256KB/CU/iter @ ~135 B/cyc) replaces LDS redundancy and
// overlaps freely with VALU/MFMA (no lockstep). V loads are issued right
// after QK MFMAs and land under softmax (manual T14).
// ---------------------------------------------------------------------------
__global__ __launch_bounds__(512) void flash_attn_kernel(
    const __hip_bfloat16* __restrict__ Q,
    const __hip_bfloat16* __restrict__ Kf,
    const __hip_bfloat16* __restrict__ Vf,
    __hip_bfloat16* __restrict__ O)
{
    // XCD-grouped decode: same-(b,h) blocks share blockIdx.x -> same XCD,
    // tile-synchronized L2 reuse; long/short blocks mixed across XCDs.
    const int p = blockIdx.y & 7;                     // pair index 0..7
    const int h = blockIdx.x + 8 * (blockIdx.y >> 3); // head 0..15
    const int b = blockIdx.z;
    const int t = threadIdx.x;
    const int w = t >> 6;                // 0..7
    const int lane = t & 63;
    const int l31 = lane & 31;
    const int hi = lane >> 5;

    const int qt = (w < 4) ? (15 - p) : p;   // this wave's q-tile
    const int wq = w & 3;
    const int qwb = qt * 128 + wq * 32;      // wave's q base (32 rows)
    const int q = qwb + l31;                 // this lane's q row
    const int my_nt = 2 * qt + 1 + (wq >> 1);// kv tiles this wave needs

    const __hip_bfloat16* Kfb = Kf + (size_t)(b * 16 + h) * 262144;
    const __hip_bfloat16* Vfb = Vf + (size_t)(b * 16 + h) * 262144;

    // Q B-frags: qf[s] = Q[q][d = 16s + 8hi + j], j=0..7
    bf16x8 qf[8];
    {
        const __hip_bfloat16* qrow = Q + (size_t)(b * SS + q) * 2048 + h * 128;
        #pragma unroll
        for (int s = 0; s < 8; s++)
            qf[s] = ld_frag(qrow + s * 16 + hi * 8);
    }

    const int loff = lane * 8;               // fragment slot (elements)
    const __hip_bfloat16* kptr = Kfb + loff; // region (kb*8+s)*512 per tile
    const __hip_bfloat16* vptr = Vfb + loff; // region (dt*4+s)*512 per tile

    float m_i = -INFINITY;   // running max, log2 domain (S * C2LOG)
    float l_i = 0.0f;
    f32x16 acc[4] = {};      // O^T: acc[dt], d = dt*32 + 8*(e>>2) + 4hi + (e&3), col q=l31

    for (int kt = 0; kt < my_nt; kt++) {
        const int kvb = kt * 64;

        // ---- K fragments: 16 coalesced 16B/lane loads straight from L2 ----
        bf16x8 kfr[2][8];
        #pragma unroll
        for (int kb = 0; kb < 2; kb++)
            #pragma unroll
            for (int s = 0; s < 8; s++)
                kfr[kb][s] = ld_frag(kptr + (kb * 8 + s) * 512);

        // ---- S^T = K * Q^T : 2 kv-blocks x 8 k-steps of 32x32x16 ----
        f32x16 st[2] = {};
        __builtin_amdgcn_s_setprio(1);
        #pragma unroll
        for (int s = 0; s < 8; s++)
            #pragma unroll
            for (int kb = 0; kb < 2; kb++)
                st[kb] = __builtin_amdgcn_mfma_f32_32x32x16_bf16(
                    kfr[kb][s], qf[s], st[kb], 0, 0, 0);
        __builtin_amdgcn_s_setprio(0);

        // ---- V fragments issued now; land under softmax (T14) ----
        bf16x8 vfr[4][4];
        #pragma unroll
        for (int dt = 0; dt < 4; dt++)
            #pragma unroll
            for (int s = 0; s < 4; s++)
                vfr[dt][s] = ld_frag(vptr + (dt * 4 + s) * 512);

        // ---- row max; causal cndmask only on the diagonal tile ----
        float tmx;
        if (kvb + 63 > qwb) {            // wave-uniform: diagonal tile
            const int thr = q - kvb - 4 * hi;   // pass iff kb*32 + 8g + r <= thr
            tmx = -INFINITY;
            #pragma unroll
            for (int kb = 0; kb < 2; kb++)
                #pragma unroll
                for (int g = 0; g < 4; g++)
                    #pragma unroll
                    for (int r = 0; r < 4; r++) {
                        const int e = g * 4 + r;
                        float v = (kb * 32 + 8 * g + r <= thr) ? st[kb][e] : -INFINITY;
                        st[kb][e] = v;
                        tmx = fmaxf(tmx, v);
                    }
        } else {                          // interior: max3-fusible tree
            tmx = fmaxf(st[0][0], st[0][1]);
            #pragma unroll
            for (int e = 2; e < 16; e += 2)
                tmx = fmaxf(fmaxf(tmx, st[0][e]), st[0][e + 1]);
            #pragma unroll
            for (int e = 0; e < 16; e += 2)
                tmx = fmaxf(fmaxf(tmx, st[1][e]), st[1][e + 1]);
        }
        tmx = fmaxf(tmx, __shfl_xor(tmx, 32));
        const float m2x = tmx * C2LOG;

        // ---- online softmax (log2 domain) + T13 defer-max ----
        const bool nosc = __all(m2x <= m_i + 8.0f);
        const float mnew = nosc ? m_i : fmaxf(m_i, m2x);
        float rs = 0.0f;
        #pragma unroll
        for (int kb = 0; kb < 2; kb++)
            #pragma unroll
            for (int e = 0; e < 16; e++) {
                float pv = exp2f(fmaf(st[kb][e], C2LOG, -mnew));
                st[kb][e] = pv;
                rs += pv;
            }
        rs += __shfl_xor(rs, 32);
        if (!nosc) {
            const float alpha = exp2f(m_i - mnew);
            m_i = mnew;
            l_i *= alpha;
            #pragma unroll
            for (int dt = 0; dt < 4; dt++)
                #pragma unroll
                for (int e = 0; e < 16; e++)
                    acc[dt][e] *= alpha;
        }
        l_i += rs;

        // ---- P -> bf16 PV B-frags in registers (T12, HW cvt_pk) ----
        uint4 af[4];
        #pragma unroll
        for (int kb = 0; kb < 2; kb++) {
            unsigned int pk[4][2];
            #pragma unroll
            for (int g = 0; g < 4; g++)
                #pragma unroll
                for (int i = 0; i < 2; i++)
                    pk[g][i] = cvt_pk_bf16(st[kb][g * 4 + 2 * i],
                                           st[kb][g * 4 + 2 * i + 1]);
            #pragma unroll
            for (int sl = 0; sl < 2; sl++) {
                uintx2 r0 = __builtin_amdgcn_permlane32_swap(
                    pk[2 * sl][0], pk[2 * sl + 1][0], false, false);
                uintx2 r1 = __builtin_amdgcn_permlane32_swap(
                    pk[2 * sl][1], pk[2 * sl + 1][1], false, false);
                af[kb * 2 + sl] = make_uint4(r0[0], r1[0], r0[1], r1[1]);
            }
        }

        // ---- O^T += V^T * P^T : 4 d-tiles x 4 kv-steps ----
        __builtin_amdgcn_s_setprio(1);
        #pragma unroll
        for (int s = 0; s < 4; s++) {
            bf16x8 pf = __builtin_bit_cast(bf16x8, af[s]);
            #pragma unroll
            for (int dt = 0; dt < 4; dt++)
                acc[dt] = __builtin_amdgcn_mfma_f32_32x32x16_bf16(
                    vfr[dt][s], pf, acc[dt], 0, 0, 0);
        }
        __builtin_amdgcn_s_setprio(0);

        kptr += 8192; vptr += 8192;
    }

    // ---- epilogue: per-lane q = l31, d = dt*32 + 8g + 4hi + r ----
    const float inv_l = 1.0f / l_i;
    __hip_bfloat16* orow = O + (size_t)(b * SS + q) * 2048 + h * 128;
    #pragma unroll
    for (int dt = 0; dt < 4; dt++)
        #pragma unroll
        for (int g = 0; g < 4; g++) {
            uint2 uu;
            uu.x = cvt_pk_bf16(acc[dt][g * 4 + 0] * inv_l, acc[dt][g * 4 + 1] * inv_l);
            uu.y = cvt_pk_bf16(acc[dt][g * 4 + 2] * inv_l, acc[dt][g * 4 + 3] * inv_l);
            *reinterpret_cast<uint2*>(orow + dt * 32 + 8 * g + 4 * hi) = uu;
        }
}

// ---------------------------------------------------------------------------
extern "C" void kernel_launch(void* const* d_in, const int* in_sizes, int n_in,
                              void* d_out, int out_size, void* d_ws, size_t ws_size,
                              hipStream_t stream)
{
    const float* hs       = (const float*)d_in[0];
    const float* w_kv_d   = (const float*)d_in[1];
    const float* w_q_d    = (const float*)d_in[2];
    const float* w_k_u    = (const float*)d_in[3];
    const float* w_q_u    = (const float*)d_in[4];
    const float* w_v_u    = (const float*)d_in[5];
    const float* w_rope_k = (const float*)d_in[6];
    const float* w_rope_q = (const float*)d_in[7];
    const float* w_o      = (const float*)d_in[8];
    float* out = (float*)d_out;

    char* p = (char*)d_ws;
    auto alloc = [&](size_t nelem) {
        __hip_bfloat16* r = (__hip_bfloat16*)p;
        p += nelem * sizeof(__hip_bfloat16);
        return r;
    };
    __hip_bfloat16* hsb  = alloc((size_t)BS * HID);        // 16 MB (reused as attn)
    __hip_bfloat16* qkvd = alloc((size_t)BS * 512);        // 4 MB
    __hip_bfloat16* WT1  = alloc((size_t)1536 * 2048);     // 6 MB
    __hip_bfloat16* WT2  = alloc((size_t)3072 * 256);      // 1.5 MB
    __hip_bfloat16* WT3  = alloc((size_t)2048 * 256);      // 1 MB
    __hip_bfloat16* WTo  = alloc((size_t)2048 * 2048);     // 8 MB
    __hip_bfloat16* Kf   = alloc((size_t)BS * HID);        // 16 MB, fragment-order K
    __hip_bfloat16* Qbuf = alloc((size_t)BS * HID);        // 16 MB
    __hip_bfloat16* Vf   = alloc((size_t)HID * BS);        // 16 MB, fragment-order V
    __hip_bfloat16* attn = hsb;   // hs dead after G1

    dim3 blk(256);

    // 0a. hs -> bf16
    convert_kernel<<<dim3((BS * HID / 8 + 255) / 256), blk, 0, stream>>>(
        hs, hsb, BS * HID / 8);
    // 0b. all weights: transpose + convert to bf16 W^T
    transpose_weights_kernel<<<dim3(8448), blk, 0, stream>>>(
        w_kv_d, w_q_d, w_rope_k, w_k_u, w_v_u, w_q_u, w_rope_q, w_o,
        WT1, WT2, WT3, WTo);

    // G1: [kv_d | q_d | krp] = hsb @ WT1^T  (N=1536, K=2048); krp -> Kf d=64..127
    gemm_bt_kernel<__hip_bfloat16><<<dim3(1536 / 128, BS / 128), blk, 0, stream>>>(
        hsb, 2048, WT1,
        qkvd, 512, 0, 0, 1.0f,
        Kf, 0, 3, 64, 1.0f,
        512, 2048);
    // G2: [k_p | v] = kv_d @ WT2^T  (N=3072, K=256); k_p -> Kf d=0..63, v -> Vf
    gemm_bt_kernel<__hip_bfloat16><<<dim3(3072 / 128, BS / 128), blk, 0, stream>>>(
        qkvd, 512, WT2,
        Kf, 0, 3, 0, 1.0f,
        Vf, 0, 4, 0, 1.0f,
        1024, 256);
    // G3: [q_p | q_rope_pre] = q_d @ WT3^T  (N=2048, K=256)
    gemm_bt_kernel<__hip_bfloat16><<<dim3(2048 / 128, BS / 128), blk, 0, stream>>>(
        qkvd + 256, 512, WT3,
        Qbuf, 2048, 1, 0, 1.0f,
        Qbuf, 2048, 1, 64, 1.0f,
        1024, 256);
    // 4. RoPE in-place (K in Kf layout, Q row-major)
    rope_kernel<<<dim3((BS * NH * 32 + 255) / 256), blk, 0, stream>>>(Kf, Qbuf);
    // 5. flash attention v17 -> attn (no LDS, no barriers, direct L2 frags)
    flash_attn_kernel<<<dim3(8, NH, BB), dim3(512), 0, stream>>>(
        Qbuf, Kf, Vf, attn);
    // G4: out = attn @ WTo^T (fp32 out)
    gemm_bt_kernel<float><<<dim3(2048 / 128, BS / 128), blk, 0, stream>>>(
        attn, 2048, WTo,
        out, 2048, 0, 0, 1.0f,
        out, 2048, 0, 0, 1.0f,
        2048, 2048);
}